// Round 2
// baseline (77.740 us; speedup 1.0000x reference)
//
#include <hip/hip_runtime.h>

#define EPS 1e-8f

namespace {
constexpr int Bc = 128;
constexpr int Tc = 128;
constexpr int Dc = 512;
constexpr int D4 = Dc / 4;                       // 128 float4 per row
constexpr int THREADS = 256;
constexpr int BLOCKS_PER_TENSOR = (Bc * D4) / THREADS;  // 64
}

// Kernel 1: partial T-sums. fpart[c][q][b][d] = sum_{t in chunk c} f_q[b][t][d]
__global__ __launch_bounds__(256) void hm_mean_kernel(
    const float* __restrict__ f0, const float* __restrict__ f1,
    const float* __restrict__ f2, const float* __restrict__ f3,
    const float* __restrict__ f4, const float* __restrict__ f5,
    const float* __restrict__ f6, const float* __restrict__ f7,
    const float* __restrict__ f8, float* __restrict__ fpart,
    int nch, int tpc)
{
    const float* fs[9] = {f0, f1, f2, f3, f4, f5, f6, f7, f8};
    const int bpt   = BLOCKS_PER_TENSOR * nch;       // blocks per tensor
    const int q     = blockIdx.x / bpt;
    const int rest  = blockIdx.x % bpt;
    const int chunk = rest / BLOCKS_PER_TENSOR;
    const int blk   = rest % BLOCKS_PER_TENSOR;
    const int idx   = blk * THREADS + threadIdx.x;   // b*D4 + d4
    const int b     = idx >> 7;                      // /D4
    const int d4    = idx & (D4 - 1);

    const float4* src = reinterpret_cast<const float4*>(fs[q])
                      + (size_t)b * Tc * D4 + (size_t)chunk * tpc * D4 + d4;

    float4 a0 = make_float4(0.f, 0.f, 0.f, 0.f);
    float4 a1 = make_float4(0.f, 0.f, 0.f, 0.f);
    float4 a2 = make_float4(0.f, 0.f, 0.f, 0.f);
    float4 a3 = make_float4(0.f, 0.f, 0.f, 0.f);
    for (int t = 0; t < tpc; t += 4) {
        float4 v0 = src[(size_t)t * D4];
        float4 v1 = src[(size_t)(t + 1) * D4];
        float4 v2 = src[(size_t)(t + 2) * D4];
        float4 v3 = src[(size_t)(t + 3) * D4];
        a0.x += v0.x; a0.y += v0.y; a0.z += v0.z; a0.w += v0.w;
        a1.x += v1.x; a1.y += v1.y; a1.z += v1.z; a1.w += v1.w;
        a2.x += v2.x; a2.y += v2.y; a2.z += v2.z; a2.w += v2.w;
        a3.x += v3.x; a3.y += v3.y; a3.z += v3.z; a3.w += v3.w;
    }
    float4 r;
    r.x = (a0.x + a1.x) + (a2.x + a3.x);
    r.y = (a0.y + a1.y) + (a2.y + a3.y);
    r.z = (a0.z + a1.z) + (a2.z + a3.z);
    r.w = (a0.w + a1.w) + (a2.w + a3.w);
    reinterpret_cast<float4*>(fpart)[(size_t)(chunk * 9 + q) * Bc * D4 + idx] = r;
}

// Kernel 2: combine partials + all the small linear algebra. One block per b.
__global__ __launch_bounds__(256) void hm_final_kernel(
    const float* __restrict__ joint, const float* __restrict__ fpart,
    float* __restrict__ out, int nch)
{
    const int b    = blockIdx.x;
    const int tid  = threadIdx.x;
    const int lane = tid & 63;
    const int wave = tid >> 6;

    __shared__ float sm_red[4][9];
    __shared__ float sm_red2[4][3];
    __shared__ float sm_num[9];
    __shared__ float sm_num2[3];

    const float invT = 1.0f / (float)Tc;

    // each thread handles d = tid and d = tid + 256
    float jd[2];
    float fm[2][9];
    float pnum[9];
    #pragma unroll
    for (int q = 0; q < 9; ++q) pnum[q] = 0.f;

    #pragma unroll
    for (int r = 0; r < 2; ++r) {
        const int d = tid + r * 256;
        jd[r] = joint[(size_t)b * Dc + d];
        #pragma unroll
        for (int q = 0; q < 9; ++q) {
            float s = 0.f;
            for (int c = 0; c < nch; ++c)
                s += fpart[((size_t)(c * 9 + q) * Bc + b) * Dc + d];
            fm[r][q] = s * invT;
            pnum[q] += jd[r] * fm[r][q];
        }
    }

    // block-reduce 9 partial dot products -> num[i,j]
    #pragma unroll
    for (int q = 0; q < 9; ++q)
        #pragma unroll
        for (int off = 32; off > 0; off >>= 1)
            pnum[q] += __shfl_down(pnum[q], off, 64);
    if (lane == 0)
        #pragma unroll
        for (int q = 0; q < 9; ++q) sm_red[wave][q] = pnum[q];
    __syncthreads();
    if (tid < 9)
        sm_num[tid] = sm_red[0][tid] + sm_red[1][tid] + sm_red[2][tid] + sm_red[3][tid];
    __syncthreads();

    // b weights
    float num[9];
    #pragma unroll
    for (int q = 0; q < 9; ++q) num[q] = sm_num[q];
    float bw[3][3];
    #pragma unroll
    for (int i = 0; i < 3; ++i) {
        const float denom = num[i * 3] + num[i * 3 + 1] + num[i * 3 + 2] + EPS;
        const float rdenom = 1.0f / denom;
        #pragma unroll
        for (int j = 0; j < 3; ++j) bw[i][j] = num[i * 3 + j] * rdenom;
    }

    // fii_mean per d (in registers) + num2 partials
    float fii[2][3];
    float pnum2[3] = {0.f, 0.f, 0.f};
    #pragma unroll
    for (int r = 0; r < 2; ++r)
        #pragma unroll
        for (int i = 0; i < 3; ++i) {
            fii[r][i] = bw[i][0] * fm[r][i * 3 + 0]
                      + bw[i][1] * fm[r][i * 3 + 1]
                      + bw[i][2] * fm[r][i * 3 + 2];
            pnum2[i] += jd[r] * fii[r][i];
        }

    // block-reduce 3 values -> num2[i]
    #pragma unroll
    for (int i = 0; i < 3; ++i)
        #pragma unroll
        for (int off = 32; off > 0; off >>= 1)
            pnum2[i] += __shfl_down(pnum2[i], off, 64);
    if (lane == 0)
        #pragma unroll
        for (int i = 0; i < 3; ++i) sm_red2[wave][i] = pnum2[i];
    __syncthreads();
    if (tid < 3)
        sm_num2[tid] = sm_red2[0][tid] + sm_red2[1][tid] + sm_red2[2][tid] + sm_red2[3][tid];
    __syncthreads();

    const float denom2 = sm_num2[0] + sm_num2[1] + sm_num2[2] + EPS;
    const float rd2 = 1.0f / denom2;
    float lam[3];
    #pragma unroll
    for (int i = 0; i < 3; ++i) lam[i] = sm_num2[i] * rd2;

    #pragma unroll
    for (int r = 0; r < 2; ++r) {
        const int d = tid + r * 256;
        out[(size_t)b * Dc + d] =
            lam[0] * fii[r][0] + lam[1] * fii[r][1] + lam[2] * fii[r][2];
    }
}

extern "C" void kernel_launch(void* const* d_in, const int* in_sizes, int n_in,
                              void* d_out, int out_size, void* d_ws, size_t ws_size,
                              hipStream_t stream) {
    const float* joint = (const float*)d_in[0];
    const float* f[9];
    for (int q = 0; q < 9; ++q) f[q] = (const float*)d_in[1 + q];
    float* out = (float*)d_out;
    float* fpart = (float*)d_ws;

    // Pick chunk count (waves in flight) that fits the scratch buffer.
    const size_t plane = (size_t)9 * Bc * Dc * sizeof(float);  // 1.18 MB per chunk
    int nch = 4;
    while (nch > 1 && (size_t)nch * plane > ws_size) nch >>= 1;
    const int tpc = Tc / nch;

    const int grid1 = 9 * BLOCKS_PER_TENSOR * nch;  // 2304 at nch=4
    hipLaunchKernelGGL(hm_mean_kernel, dim3(grid1), dim3(THREADS), 0, stream,
                       f[0], f[1], f[2], f[3], f[4], f[5], f[6], f[7], f[8],
                       fpart, nch, tpc);
    hipLaunchKernelGGL(hm_final_kernel, dim3(Bc), dim3(THREADS), 0, stream,
                       joint, fpart, out, nch);
}

// Round 3
// 63.816 us; speedup vs baseline: 1.2182x; 1.2182x over previous
//
#include <hip/hip_runtime.h>

#define EPS 1e-8f

namespace {
constexpr int Bc = 128;
constexpr int Tc = 128;
constexpr int Dc = 512;
constexpr int D4 = Dc / 4;                       // 128 float4 per row
constexpr int THREADS = 256;
constexpr int BLOCKS_PER_TENSOR = (Bc * D4) / THREADS;  // 64
}

// Kernel 1: partial T-sums. fpart[c][q][b][d] = sum_{t in chunk c} f_q[b][t][d]
// TPC = rows per chunk (compile-time so the loop fully pipelines).
template<int TPC>
__global__ __launch_bounds__(256) void hm_mean_kernel(
    const float* __restrict__ f0, const float* __restrict__ f1,
    const float* __restrict__ f2, const float* __restrict__ f3,
    const float* __restrict__ f4, const float* __restrict__ f5,
    const float* __restrict__ f6, const float* __restrict__ f7,
    const float* __restrict__ f8, float* __restrict__ fpart)
{
    constexpr int NCH = Tc / TPC;
    const float* fs[9] = {f0, f1, f2, f3, f4, f5, f6, f7, f8};
    const int bpt   = BLOCKS_PER_TENSOR * NCH;       // blocks per tensor
    const int q     = blockIdx.x / bpt;
    const int rest  = blockIdx.x % bpt;
    const int chunk = rest / BLOCKS_PER_TENSOR;
    const int blk   = rest % BLOCKS_PER_TENSOR;
    const int idx   = blk * THREADS + threadIdx.x;   // b*D4 + d4
    const int b     = idx >> 7;                      // /D4
    const int d4    = idx & (D4 - 1);

    const float4* src = reinterpret_cast<const float4*>(fs[q])
                      + (size_t)b * Tc * D4 + (size_t)chunk * TPC * D4 + d4;

    float4 acc[4];
    #pragma unroll
    for (int u = 0; u < 4; ++u) acc[u] = make_float4(0.f, 0.f, 0.f, 0.f);

    // 8 loads staged before any accumulate -> 8-deep MLP per wave.
    for (int t0 = 0; t0 < TPC; t0 += 8) {
        float4 buf[8];
        #pragma unroll
        for (int u = 0; u < 8; ++u)
            buf[u] = src[(size_t)(t0 + u) * D4];
        #pragma unroll
        for (int u = 0; u < 8; ++u) {
            acc[u & 3].x += buf[u].x;
            acc[u & 3].y += buf[u].y;
            acc[u & 3].z += buf[u].z;
            acc[u & 3].w += buf[u].w;
        }
    }
    float4 r;
    r.x = (acc[0].x + acc[1].x) + (acc[2].x + acc[3].x);
    r.y = (acc[0].y + acc[1].y) + (acc[2].y + acc[3].y);
    r.z = (acc[0].z + acc[1].z) + (acc[2].z + acc[3].z);
    r.w = (acc[0].w + acc[1].w) + (acc[2].w + acc[3].w);
    reinterpret_cast<float4*>(fpart)[(size_t)(chunk * 9 + q) * Bc * D4 + idx] = r;
}

// Kernel 2: combine partials + small linear algebra. One block per b.
__global__ __launch_bounds__(256) void hm_final_kernel(
    const float* __restrict__ joint, const float* __restrict__ fpart,
    float* __restrict__ out, int nch)
{
    const int b    = blockIdx.x;
    const int tid  = threadIdx.x;
    const int lane = tid & 63;
    const int wave = tid >> 6;

    __shared__ float sm_red[4][9];
    __shared__ float sm_red2[4][3];
    __shared__ float sm_num[9];
    __shared__ float sm_num2[3];

    const float invT = 1.0f / (float)Tc;

    float jd[2];
    float fm[2][9];
    float pnum[9];
    #pragma unroll
    for (int q = 0; q < 9; ++q) pnum[q] = 0.f;

    #pragma unroll
    for (int r = 0; r < 2; ++r) {
        const int d = tid + r * 256;
        jd[r] = joint[(size_t)b * Dc + d];
        #pragma unroll
        for (int q = 0; q < 9; ++q) {
            float s = 0.f;
            for (int c = 0; c < nch; ++c)
                s += fpart[((size_t)(c * 9 + q) * Bc + b) * Dc + d];
            fm[r][q] = s * invT;
            pnum[q] += jd[r] * fm[r][q];
        }
    }

    #pragma unroll
    for (int q = 0; q < 9; ++q)
        #pragma unroll
        for (int off = 32; off > 0; off >>= 1)
            pnum[q] += __shfl_down(pnum[q], off, 64);
    if (lane == 0)
        #pragma unroll
        for (int q = 0; q < 9; ++q) sm_red[wave][q] = pnum[q];
    __syncthreads();
    if (tid < 9)
        sm_num[tid] = sm_red[0][tid] + sm_red[1][tid] + sm_red[2][tid] + sm_red[3][tid];
    __syncthreads();

    float num[9];
    #pragma unroll
    for (int q = 0; q < 9; ++q) num[q] = sm_num[q];
    float bw[3][3];
    #pragma unroll
    for (int i = 0; i < 3; ++i) {
        const float denom = num[i * 3] + num[i * 3 + 1] + num[i * 3 + 2] + EPS;
        const float rdenom = 1.0f / denom;
        #pragma unroll
        for (int j = 0; j < 3; ++j) bw[i][j] = num[i * 3 + j] * rdenom;
    }

    float fii[2][3];
    float pnum2[3] = {0.f, 0.f, 0.f};
    #pragma unroll
    for (int r = 0; r < 2; ++r)
        #pragma unroll
        for (int i = 0; i < 3; ++i) {
            fii[r][i] = bw[i][0] * fm[r][i * 3 + 0]
                      + bw[i][1] * fm[r][i * 3 + 1]
                      + bw[i][2] * fm[r][i * 3 + 2];
            pnum2[i] += jd[r] * fii[r][i];
        }

    #pragma unroll
    for (int i = 0; i < 3; ++i)
        #pragma unroll
        for (int off = 32; off > 0; off >>= 1)
            pnum2[i] += __shfl_down(pnum2[i], off, 64);
    if (lane == 0)
        #pragma unroll
        for (int i = 0; i < 3; ++i) sm_red2[wave][i] = pnum2[i];
    __syncthreads();
    if (tid < 3)
        sm_num2[tid] = sm_red2[0][tid] + sm_red2[1][tid] + sm_red2[2][tid] + sm_red2[3][tid];
    __syncthreads();

    const float denom2 = sm_num2[0] + sm_num2[1] + sm_num2[2] + EPS;
    const float rd2 = 1.0f / denom2;
    float lam[3];
    #pragma unroll
    for (int i = 0; i < 3; ++i) lam[i] = sm_num2[i] * rd2;

    #pragma unroll
    for (int r = 0; r < 2; ++r) {
        const int d = tid + r * 256;
        out[(size_t)b * Dc + d] =
            lam[0] * fii[r][0] + lam[1] * fii[r][1] + lam[2] * fii[r][2];
    }
}

extern "C" void kernel_launch(void* const* d_in, const int* in_sizes, int n_in,
                              void* d_out, int out_size, void* d_ws, size_t ws_size,
                              hipStream_t stream) {
    const float* joint = (const float*)d_in[0];
    const float* f[9];
    for (int q = 0; q < 9; ++q) f[q] = (const float*)d_in[1 + q];
    float* out = (float*)d_out;
    float* fpart = (float*)d_ws;

    const size_t plane = (size_t)9 * Bc * Dc * sizeof(float);  // 1.18 MB per chunk
    int nch;
    if (ws_size >= 2 * plane) nch = 2;
    else                      nch = 1;

    const int grid1 = 9 * BLOCKS_PER_TENSOR * nch;
    if (nch == 2) {
        hipLaunchKernelGGL((hm_mean_kernel<Tc / 2>), dim3(grid1), dim3(THREADS), 0, stream,
                           f[0], f[1], f[2], f[3], f[4], f[5], f[6], f[7], f[8], fpart);
    } else {
        hipLaunchKernelGGL((hm_mean_kernel<Tc>), dim3(grid1), dim3(THREADS), 0, stream,
                           f[0], f[1], f[2], f[3], f[4], f[5], f[6], f[7], f[8], fpart);
    }
    hipLaunchKernelGGL(hm_final_kernel, dim3(Bc), dim3(THREADS), 0, stream,
                       joint, fpart, out, nch);
}

// Round 4
// 54.036 us; speedup vs baseline: 1.4387x; 1.1810x over previous
//
#include <hip/hip_runtime.h>

#define EPS 1e-8f

typedef float f4 __attribute__((ext_vector_type(4)));

namespace {
constexpr int Bc = 128;
constexpr int Tc = 128;
constexpr int Dc = 512;
constexpr int D4 = Dc / 4;                        // 128 float4 per row
constexpr int COLS_PER_TENSOR = Bc * D4;          // 16384 (b,d4) columns
constexpr int THREADS1 = 64;                      // one wave per block
constexpr int GRID1 = 9 * COLS_PER_TENSOR / THREADS1;  // 2304 = 9 blocks/CU exactly
}

// Kernel 1: fmean[q][b][d] = sum_t f_q[b][t][d]  (divide by T happens in kernel 2)
// One thread per (q,b,d4) column; 16-deep explicit load staging for MLP.
__global__ __launch_bounds__(64, 2) void hm_mean_kernel(
    const float* __restrict__ f0, const float* __restrict__ f1,
    const float* __restrict__ f2, const float* __restrict__ f3,
    const float* __restrict__ f4_, const float* __restrict__ f5,
    const float* __restrict__ f6, const float* __restrict__ f7,
    const float* __restrict__ f8, float* __restrict__ fmean)
{
    const float* fs[9] = {f0, f1, f2, f3, f4_, f5, f6, f7, f8};
    const int gid = blockIdx.x * THREADS1 + threadIdx.x;   // 0 .. 147455
    const int q   = gid >> 14;                             // / 16384
    const int idx = gid & (COLS_PER_TENSOR - 1);           // b*D4 + d4
    const int b   = idx >> 7;                              // / D4
    const int d4  = idx & (D4 - 1);

    const f4* src = reinterpret_cast<const f4*>(fs[q])
                  + (size_t)b * Tc * D4 + d4;

    f4 acc[4];
    #pragma unroll
    for (int u = 0; u < 4; ++u) acc[u] = (f4){0.f, 0.f, 0.f, 0.f};

    for (int t0 = 0; t0 < Tc; t0 += 16) {
        f4 buf[16];
        #pragma unroll
        for (int u = 0; u < 16; ++u)
            buf[u] = __builtin_nontemporal_load(src + (size_t)(t0 + u) * D4);
        #pragma unroll
        for (int u = 0; u < 16; ++u)
            acc[u & 3] += buf[u];
    }

    f4 r = (acc[0] + acc[1]) + (acc[2] + acc[3]);
    reinterpret_cast<f4*>(fmean)[(size_t)q * COLS_PER_TENSOR + idx] = r;
}

// Kernel 2: all the small linear algebra. One block (256 thr) per batch element b.
__global__ __launch_bounds__(256) void hm_final_kernel(
    const float* __restrict__ joint, const float* __restrict__ fmean,
    float* __restrict__ out)
{
    const int b    = blockIdx.x;
    const int tid  = threadIdx.x;
    const int lane = tid & 63;
    const int wave = tid >> 6;

    __shared__ float sm_red[4][9];
    __shared__ float sm_red2[4][3];
    __shared__ float sm_num[9];
    __shared__ float sm_num2[3];

    const float invT = 1.0f / (float)Tc;

    float jd[2];
    float fm[2][9];
    float pnum[9];
    #pragma unroll
    for (int q = 0; q < 9; ++q) pnum[q] = 0.f;

    #pragma unroll
    for (int r = 0; r < 2; ++r) {
        const int d = tid + r * 256;
        jd[r] = joint[(size_t)b * Dc + d];
        #pragma unroll
        for (int q = 0; q < 9; ++q) {
            fm[r][q] = fmean[((size_t)q * Bc + b) * Dc + d] * invT;
            pnum[q] += jd[r] * fm[r][q];
        }
    }

    #pragma unroll
    for (int q = 0; q < 9; ++q)
        #pragma unroll
        for (int off = 32; off > 0; off >>= 1)
            pnum[q] += __shfl_down(pnum[q], off, 64);
    if (lane == 0)
        #pragma unroll
        for (int q = 0; q < 9; ++q) sm_red[wave][q] = pnum[q];
    __syncthreads();
    if (tid < 9)
        sm_num[tid] = sm_red[0][tid] + sm_red[1][tid] + sm_red[2][tid] + sm_red[3][tid];
    __syncthreads();

    float num[9];
    #pragma unroll
    for (int q = 0; q < 9; ++q) num[q] = sm_num[q];
    float bw[3][3];
    #pragma unroll
    for (int i = 0; i < 3; ++i) {
        const float denom = num[i * 3] + num[i * 3 + 1] + num[i * 3 + 2] + EPS;
        const float rdenom = 1.0f / denom;
        #pragma unroll
        for (int j = 0; j < 3; ++j) bw[i][j] = num[i * 3 + j] * rdenom;
    }

    float fii[2][3];
    float pnum2[3] = {0.f, 0.f, 0.f};
    #pragma unroll
    for (int r = 0; r < 2; ++r)
        #pragma unroll
        for (int i = 0; i < 3; ++i) {
            fii[r][i] = bw[i][0] * fm[r][i * 3 + 0]
                      + bw[i][1] * fm[r][i * 3 + 1]
                      + bw[i][2] * fm[r][i * 3 + 2];
            pnum2[i] += jd[r] * fii[r][i];
        }

    #pragma unroll
    for (int i = 0; i < 3; ++i)
        #pragma unroll
        for (int off = 32; off > 0; off >>= 1)
            pnum2[i] += __shfl_down(pnum2[i], off, 64);
    if (lane == 0)
        #pragma unroll
        for (int i = 0; i < 3; ++i) sm_red2[wave][i] = pnum2[i];
    __syncthreads();
    if (tid < 3)
        sm_num2[tid] = sm_red2[0][tid] + sm_red2[1][tid] + sm_red2[2][tid] + sm_red2[3][tid];
    __syncthreads();

    const float denom2 = sm_num2[0] + sm_num2[1] + sm_num2[2] + EPS;
    const float rd2 = 1.0f / denom2;
    float lam[3];
    #pragma unroll
    for (int i = 0; i < 3; ++i) lam[i] = sm_num2[i] * rd2;

    #pragma unroll
    for (int r = 0; r < 2; ++r) {
        const int d = tid + r * 256;
        out[(size_t)b * Dc + d] =
            lam[0] * fii[r][0] + lam[1] * fii[r][1] + lam[2] * fii[r][2];
    }
}

extern "C" void kernel_launch(void* const* d_in, const int* in_sizes, int n_in,
                              void* d_out, int out_size, void* d_ws, size_t ws_size,
                              hipStream_t stream) {
    const float* joint = (const float*)d_in[0];
    const float* f[9];
    for (int q = 0; q < 9; ++q) f[q] = (const float*)d_in[1 + q];
    float* out = (float*)d_out;
    float* fmean = (float*)d_ws;  // 9*B*D floats = 1.18 MB (T-sums, not yet /T)

    hipLaunchKernelGGL(hm_mean_kernel, dim3(GRID1), dim3(THREADS1), 0, stream,
                       f[0], f[1], f[2], f[3], f[4], f[5], f[6], f[7], f[8], fmean);
    hipLaunchKernelGGL(hm_final_kernel, dim3(Bc), dim3(256), 0, stream,
                       joint, fmean, out);
}